// Round 3
// baseline (556.832 us; speedup 1.0000x reference)
//
#include <hip/hip_runtime.h>
#include <stdint.h>

#define B 16
#define T 1024
#define V 4096
#define P 100
#define L 128

// Kernel 1: partial scores. 4 waves per (b,p); wave w covers tokens
// [w*256, (w+1)*256). One int4 path read per lane -> 4 independent gathers.
// (log-softmax normalizer cancels in the softmax over p, so it is skipped)
__global__ __launch_bounds__(256) void scores4_kernel(
    const float* __restrict__ emissions,
    const int* __restrict__ emissions_lengths,
    const int* __restrict__ paths,
    float* __restrict__ scores_part)     // (B*P, 4)
{
    int gid = blockIdx.x * blockDim.x + threadIdx.x;
    int wave = gid >> 6;
    int lane = threadIdx.x & 63;
    if (wave >= B * P * 4) return;
    int w  = wave & 3;
    int bp = wave >> 2;
    int b  = bp / P;
    int len = emissions_lengths[b];
    const int4* path4 = (const int4*)(paths + (size_t)bp * T);
    int4 tk = path4[w * 64 + lane];              // coalesced 16B, tokens 4i..4i+3
    int tbase = 4 * (w * 64 + lane);
    const float* em = emissions + (size_t)b * T * V;

    float acc = 0.f;
    if (tbase + 0 < len) acc += em[(size_t)(tbase + 0) * V + tk.x];
    if (tbase + 1 < len) acc += em[(size_t)(tbase + 1) * V + tk.y];
    if (tbase + 2 < len) acc += em[(size_t)(tbase + 2) * V + tk.z];
    if (tbase + 3 < len) acc += em[(size_t)(tbase + 3) * V + tk.w];

    #pragma unroll
    for (int off = 32; off; off >>= 1) acc += __shfl_down(acc, off, 64);
    if (lane == 0) scores_part[bp * 4 + w] = acc;
}

// Kernel 2: wers via anti-diagonal Levenshtein DP, TWO problems per wave.
// Wave w handles (b,p) = 2w and 2w+1 (same b since P is even), so len/ll/
// labels and all index arithmetic are shared; the two DP chains are fully
// independent -> their shuffle/LDS latencies overlap each other's VALU.
__global__ __launch_bounds__(256) void wer2_kernel(
    const int* __restrict__ emissions_lengths,
    const int* __restrict__ labels,
    const int* __restrict__ labels_length,
    const int* __restrict__ paths,
    float* __restrict__ wers)
{
    __shared__ unsigned short toks[8][1024];     // 16 KB: 4 waves x 2 problems
    int wid  = threadIdx.x >> 6;                 // wave in block, 0..3
    int wave = blockIdx.x * 4 + wid;             // 0..799
    int lane = threadIdx.x & 63;
    int pa = wave * 2;
    int pb = wave * 2 + 1;
    int b  = pa / P;                             // same for pb (P even)
    int len = emissions_lengths[b];
    int ll  = labels_length[b];                  // setup guarantees ll >= 64
    const int* patha = paths + (size_t)pa * T;
    const int* pathb = paths + (size_t)pb * T;
    unsigned short* ta = toks[wid * 2];
    unsigned short* tb = toks[wid * 2 + 1];

    // ---- Phase 1: CTC-collapse both paths into LDS (interleaved) ----
    unsigned long long lmask = (1ull << lane) - 1ull;
    int prevA = -1, prevB = -1, baseA = 0, baseB = 0;
    for (int t0 = 0; t0 < len; t0 += 64) {
        int ca = patha[t0 + lane];               // coalesced; t0+lane <= 1023
        int cb = pathb[t0 + lane];
        int cpa = __shfl_up(ca, 1, 64); if (lane == 0) cpa = prevA;
        int cpb = __shfl_up(cb, 1, 64); if (lane == 0) cpb = prevB;
        bool iva = (ca != 0) && (ca != cpa) && (t0 + lane < len);
        bool ivb = (cb != 0) && (cb != cpb) && (t0 + lane < len);
        unsigned long long ma = __ballot(iva);
        unsigned long long mb = __ballot(ivb);
        if (iva) ta[baseA + __popcll(ma & lmask)] = (unsigned short)ca;
        if (ivb) tb[baseB + __popcll(mb & lmask)] = (unsigned short)cb;
        baseA += __popcll(ma);
        baseB += __popcll(mb);
        prevA = __shfl(ca, 63, 64);
        prevB = __shfl(cb, 63, 64);
    }
    int Sa = baseA, Sb = baseB;

    // ---- Phase 2: diagonal DP, lane owns columns j1=2i+1, j2=2i+2 ----
    int j1 = 2 * lane + 1;
    int j2 = 2 * lane + 2;
    int r1 = labels[b * L + 2 * lane];
    int r2 = labels[b * L + 2 * lane + 1];

    int A1a = j1, B1a = j1, A2a = j2, B2a = j2;  // problem a state
    int A1b = j1, B1b = j1, A2b = j2, B2b = j2;  // problem b state
    int tok1a = 0, tok2a = 0, tok1b = 0, tok2b = 0;
    int idx = 1 - 2 * lane - 2;                  // token prefetch index for d=1
    int tna = ta[idx & 1023];
    int tnb = tb[idx & 1023];
    int dmax = max(Sa, Sb) + ll;

    for (int d = 1; d <= dmax; d++) {
        int pka = (A2a << 16) | (B2a & 0xffff);
        int pkb = (A2b << 16) | (B2b & 0xffff);
        int ua = __shfl_up(pka, 1, 64);          // two independent bpermutes
        int ub = __shfl_up(pkb, 1, 64);
        int upAa, upBa, upAb, upBb;
        if (lane == 0) { upAa = d - 1; upBa = d - 2; upAb = d - 1; upBb = d - 2; }
        else {
            upAa = ((unsigned)ua) >> 16; upBa = ua & 0xffff;
            upAb = ((unsigned)ub) >> 16; upBb = ub & 0xffff;
        }

        tok2a = tok1a; tok1a = tna;
        tok2b = tok1b; tok1b = tnb;
        idx++;
        tna = ta[idx & 1023];                    // off-chain prefetch
        tnb = tb[idx & 1023];

        int t1 = d - j1;                         // shared between problems
        int t2 = d - j2;
        bool pre1 = (t1 <= 0), pre2 = (t2 <= 0);

        int n1a = min(min(A1a, upAa) + 1, upBa + (tok1a != r1));
        if (pre1) n1a = j1; else if (t1 > Sa) n1a = A1a;
        int n2a = min(min(A2a, A1a) + 1, B1a + (tok2a != r2));
        if (pre2) n2a = j2; else if (t2 > Sa) n2a = A2a;
        B1a = A1a; A1a = n1a; B2a = A2a; A2a = n2a;

        int n1b = min(min(A1b, upAb) + 1, upBb + (tok1b != r1));
        if (pre1) n1b = j1; else if (t1 > Sb) n1b = A1b;
        int n2b = min(min(A2b, A1b) + 1, B1b + (tok2b != r2));
        if (pre2) n2b = j2; else if (t2 > Sb) n2b = A2b;
        B1b = A1b; A1b = n1b; B2b = A2b; A2b = n2b;
    }

    int li1 = (ll - 1) >> 1;                     // ll odd  -> column ll = j1
    int li2 = (ll - 2) >> 1;                     // ll even -> column ll = j2
    int va_a = __shfl(A1a, li1, 64);
    int vb_a = __shfl(A2a, li2, 64);
    int va_b = __shfl(A1b, li1, 64);
    int vb_b = __shfl(A2b, li2, 64);
    if (lane == 0) {
        wers[pa] = (float)((ll & 1) ? va_a : vb_a);
        wers[pb] = (float)((ll & 1) ? va_b : vb_b);
    }
}

// Kernel 3: out = sum_b sum_p softmax_p(scores[b,:])[p] * wers[b,p]
__global__ __launch_bounds__(1024) void reduce_kernel(
    const float* __restrict__ scores_part,        // (B*P, 4)
    const float* __restrict__ wers,
    float* __restrict__ out)
{
    __shared__ float contrib[B];
    int lane = threadIdx.x & 63;
    int b = threadIdx.x >> 6;                     // 16 waves, one per batch

    int p1 = b * P + lane;
    float s1 = scores_part[p1 * 4 + 0] + scores_part[p1 * 4 + 1]
             + scores_part[p1 * 4 + 2] + scores_part[p1 * 4 + 3];
    float w1 = wers[p1];
    bool has2 = lane < (P - 64);
    int p2 = b * P + 64 + (has2 ? lane : 0);
    float s2 = has2 ? (scores_part[p2 * 4 + 0] + scores_part[p2 * 4 + 1]
                     + scores_part[p2 * 4 + 2] + scores_part[p2 * 4 + 3])
                    : -3.4e38f;
    float w2 = has2 ? wers[p2] : 0.f;

    float m = fmaxf(s1, s2);
    #pragma unroll
    for (int off = 32; off; off >>= 1) m = fmaxf(m, __shfl_xor(m, off, 64));
    float e1 = expf(s1 - m);
    float e2 = has2 ? expf(s2 - m) : 0.f;
    float num = e1 * w1 + e2 * w2;
    float den = e1 + e2;
    #pragma unroll
    for (int off = 32; off; off >>= 1) {
        num += __shfl_xor(num, off, 64);
        den += __shfl_xor(den, off, 64);
    }
    if (lane == 0) contrib[b] = num / den;
    __syncthreads();
    if (threadIdx.x == 0) {
        float s = 0.f;
        #pragma unroll
        for (int i = 0; i < B; i++) s += contrib[i];
        out[0] = s;
    }
}

extern "C" void kernel_launch(void* const* d_in, const int* in_sizes, int n_in,
                              void* d_out, int out_size, void* d_ws, size_t ws_size,
                              hipStream_t stream) {
    const float* emissions          = (const float*)d_in[0];
    const int*   emissions_lengths  = (const int*)d_in[1];
    const int*   labels             = (const int*)d_in[2];
    const int*   labels_length      = (const int*)d_in[3];
    const int*   paths              = (const int*)d_in[4];
    float* out = (float*)d_out;

    float* scores_part = (float*)d_ws;            // B*P*4 floats
    float* wers        = scores_part + B * P * 4; // B*P floats

    scores4_kernel<<<(B * P * 4 * 64) / 256, 256, 0, stream>>>(
        emissions, emissions_lengths, paths, scores_part);
    wer2_kernel<<<(B * P / 2 * 64) / 256, 256, 0, stream>>>(
        emissions_lengths, labels, labels_length, paths, wers);
    reduce_kernel<<<1, 1024, 0, stream>>>(scores_part, wers, out);
}